// Round 8
// baseline (152.689 us; speedup 1.0000x reference)
//
#include <hip/hip_runtime.h>
#include <stdint.h>

#define N_CAND 25200
#define NB 16
#define ROW 85
#define TK 1024
#define MAXDET 300
#define CAP 2048
#define BITS_LO 0x3E800000u
#define TRI_WORDS 7680   // 64 * (15+14+...+0)

typedef unsigned long long u64;
typedef unsigned int u32;

static __device__ __forceinline__ u64 u64min(u64 a, u64 b) { return a < b ? a : b; }
static __device__ __forceinline__ u64 u64max(u64 a, u64 b) { return a > b ? a : b; }
static __device__ __forceinline__ int triBase(int w) { return 64 * (15 * w - (w * (w - 1)) / 2); }

// ---------------- K0: zero ghist (replaces pathological hipMemsetAsync) ----------------
__global__ __launch_bounds__(256) void zero_kernel(uint4* __restrict__ ghist4)
{
    const int i = blockIdx.x * 256 + threadIdx.x;    // 8192 threads x 16B = 128 KB
    ghist4[i] = make_uint4(0u, 0u, 0u, 0u);
}

// ---------------- K1: score + key + fused per-batch histogram ----------------
__global__ __launch_bounds__(256, 8) void score_kernel(const float* __restrict__ pred,
                                                       u64* __restrict__ keys,
                                                       u32* __restrict__ ghist)
{
#pragma clang fp contract(off)
    __shared__ float tile[64 * ROW];                 // 21.76 KB -> 7 blocks/CU
    const int tid = threadIdx.x;
    const int row0 = blockIdx.x * 64;                // 6300 blocks
    const float4* src = (const float4*)(pred + (size_t)row0 * ROW);
    float4* dst = (float4*)tile;
#pragma unroll
    for (int i = 0; i < 6; ++i) {
        int idx = tid + (i << 8);
        if (idx < (64 * ROW) / 4) dst[idx] = src[idx];
    }
    __syncthreads();

    const int r = tid >> 2, sub = tid & 3;
    const float* rowp = tile + r * ROW;
    const float obj = rowp[4];                       // 4-lane broadcast
    const int base = 5 + sub * 20;
    float bv = obj * rowp[base];                     // products, exactly like reference
    int bi = base - 5;
#pragma unroll
    for (int c = 1; c < 20; ++c) {
        float p = obj * rowp[base + c];
        if (p > bv) { bv = p; bi = base - 5 + c; }   // strict > : first occurrence
    }
#pragma unroll
    for (int off = 1; off <= 2; off <<= 1) {         // merge 4 sub-lanes; tie -> lower idx
        float ov = __shfl_xor(bv, off, 64);
        int   oi = __shfl_xor(bi, off, 64);
        if (ov > bv || (ov == bv && oi < bi)) { bv = ov; bi = oi; }
    }
    if (sub == 0) {
        int w = row0 + r;
        u32 b = (u32)w / N_CAND;                     // magic-mul
        u32 n = (u32)w - b * N_CAND;
        u64 key = 0;
        if (obj > 0.25f && bv > 0.25f) {
            u32 bits = __float_as_uint(bv);
            key = ((u64)bits << 32) | (((u64)(25199u - n)) << 7) | (u32)bi;
            int bin = (int)((bits - BITS_LO) >> 13);
            bin = bin < 0 ? 0 : (bin > 2047 ? 2047 : bin);
            atomicAdd(&ghist[(b << 11) + (u32)bin], 1u);
        }
        keys[w] = key;                               // desc sort => conf desc, n asc
    }
}

// ---------------- K2: per-batch threshold + gather + hybrid bitonic sort -> SoA ----------------
__global__ __launch_bounds__(1024) void topk_kernel(const float* __restrict__ pred,
                                                    const u64* __restrict__ keys,
                                                    const u32* __restrict__ ghist,
                                                    float4* __restrict__ soaA,
                                                    float4* __restrict__ soaB)
{
#pragma clang fp contract(off)
    __shared__ u64 sbuf[CAP];                        // 16 KB
    __shared__ u32 histA[2048];                      // 8 KB
    __shared__ u32 histB[2048];                      // 8 KB
    __shared__ u32 s_t;
    __shared__ int s_cnt;

    const int tid = threadIdx.x;
    const int b = blockIdx.x;
    const u64* kb = keys + (size_t)b * N_CAND;
    const float* pb = pred + (size_t)b * N_CAND * ROW;

    for (int i = tid; i < 2048; i += 1024) histA[i] = ghist[(b << 11) + i];
    if (tid == 0) { s_cnt = 0; s_t = 0; }
    __syncthreads();

    // suffix sum (Hillis-Steele, 11 passes)
    u32* srcp = histA; u32* dstp = histB;
    for (int step = 1; step < 2048; step <<= 1) {
        for (int i = tid; i < 2048; i += 1024)
            dstp[i] = srcp[i] + ((i + step < 2048) ? srcp[i + step] : 0u);
        __syncthreads();
        u32* t = srcp; srcp = dstp; dstp = t;
    }
    for (int i = tid; i < 2048; i += 1024) {
        u32 S = srcp[i];
        if (S >= TK && (i == 2047 || srcp[i + 1] < TK)) s_t = (u32)i;
    }
    __syncthreads();
    const u32 thr = BITS_LO + (s_t << 13);

    // gather candidates >= threshold bin
    for (int n = tid; n < N_CAND; n += 1024) {
        u64 k = kb[n];
        if ((u32)(k >> 32) >= thr) {
            int pos = atomicAdd(&s_cnt, 1);
            if (pos < CAP) sbuf[pos] = k;
        }
    }
    __syncthreads();
    int cnt = s_cnt; if (cnt > CAP) cnt = CAP;
    for (int i = tid; i < CAP; i += 1024) if (i >= cnt) sbuf[i] = 0ull;
    __syncthreads();

    // hybrid bitonic sort ascending, 2 elems/thread
    {
        const int E0 = tid << 1;
        u64 e0 = sbuf[E0], e1 = sbuf[E0 + 1];
        for (int k = 2; k <= CAP; k <<= 1) {
            for (int j = k >> 1; j > 0; j >>= 1) {
                const bool asc = ((E0 & k) == 0);
                if (j >= 128) {
                    __syncthreads();
                    sbuf[E0] = e0; sbuf[E0 + 1] = e1;
                    __syncthreads();
                    u64 p0 = sbuf[E0 ^ j], p1 = sbuf[(E0 + 1) ^ j];
                    const bool low = ((E0 & j) == 0);
                    e0 = (asc == low) ? u64min(e0, p0) : u64max(e0, p0);
                    e1 = (asc == low) ? u64min(e1, p1) : u64max(e1, p1);
                } else if (j >= 2) {
                    const int l = j >> 1;
                    u64 p0 = __shfl_xor(e0, l, 64);
                    u64 p1 = __shfl_xor(e1, l, 64);
                    const bool low = ((E0 & j) == 0);
                    e0 = (asc == low) ? u64min(e0, p0) : u64max(e0, p0);
                    e1 = (asc == low) ? u64min(e1, p1) : u64max(e1, p1);
                } else {
                    u64 mn = u64min(e0, e1), mx = u64max(e0, e1);
                    e0 = asc ? mn : mx;
                    e1 = asc ? mx : mn;
                }
            }
        }
        __syncthreads();
        sbuf[E0] = e0; sbuf[E0 + 1] = e1;
        __syncthreads();
    }

    // extract top-1024 (slot 0 = best), gather boxes, write SoA
    {
        const int i = tid;
        u64 k = sbuf[CAP - 1 - i];
        u32 bits = (u32)(k >> 32);
        float4 A, Bv;
        if (bits) {
            u32 lo = (u32)k;
            u32 n = 25199u - (lo >> 7);
            float c = (float)(lo & 127u);
            const float* rp = pb + (size_t)n * ROW;
            float x = rp[0], y = rp[1], ww = rp[2], hh = rp[3];
            float hw = ww * 0.5f, hv = hh * 0.5f;
            float x1 = x - hw, y1 = y - hv, x2 = x + hw, y2 = y + hv;
            float offc = c * 4096.0f;
            float area = ((x2 + offc) - (x1 + offc)) * ((y2 + offc) - (y1 + offc));
            A = make_float4(x1, y1, x2, y2);
            Bv = make_float4(area, __uint_as_float(bits), c, 0.0f);
        } else {
            A = make_float4(0.0f, 0.0f, 0.0f, 0.0f);
            Bv = make_float4(0.0f, -1.0f, 0.0f, 0.0f);
        }
        soaA[b * TK + i] = A;
        soaB[b * TK + i] = Bv;
    }
}

// ---------------- K3: suppression matrix -> upper-triangular words + diagonal words ----------------
__global__ __launch_bounds__(512) void mask_kernel(const float4* __restrict__ soaA,
                                                   const float4* __restrict__ soaB,
                                                   u64* __restrict__ tri,
                                                   u64* __restrict__ diagArr)
{
#pragma clang fp contract(off)
    __shared__ float4 cA[TK];                        // 16 KB
    __shared__ float4 cB[TK];                        // 16 KB
    const int tid = threadIdx.x;
    const int b = blockIdx.y;
    const int wi = blockIdx.x;                       // window index == rows [wi*64, wi*64+64)
    const int rbase = wi << 6;
    for (int i = tid; i < TK; i += 512) { cA[i] = soaA[b * TK + i]; cB[i] = soaB[b * TK + i]; }
    __syncthreads();

    u64* trib = tri + (size_t)b * TRI_WORDS;
    const int Bw = triBase(wi);
    const int s = 15 - wi;

    const int wave = tid >> 6, lane = tid & 63;
    for (int rr = 0; rr < 8; ++rr) {
        int i = rbase + (wave << 3) + rr;
        int r = i & 63;
        float4 P = cA[i]; float4 Pb = cB[i];         // broadcast reads
        float offp = Pb.z * 4096.0f;
        float px1 = P.x + offp, py1 = P.y + offp, px2 = P.z + offp, py2 = P.w + offp;
        float parea = Pb.x;
        u64 myword = 0;
        for (int word = wi; word < 16; ++word) {     // words < wi never read downstream
            int j = (word << 6) + lane;
            float4 Q = cA[j]; float4 Qb = cB[j];
            float offj = Qb.z * 4096.0f;
            float qx1 = Q.x + offj, qy1 = Q.y + offj, qx2 = Q.z + offj, qy2 = Q.w + offj;
            float ltx = fmaxf(px1, qx1), lty = fmaxf(py1, qy1);
            float rbx = fminf(px2, qx2), rby = fminf(py2, qy2);
            float w2 = fmaxf(rbx - ltx, 0.0f), h2 = fmaxf(rby - lty, 0.0f);
            float inter = w2 * h2;
            float iou = inter / (parea + Qb.x - inter + 1e-9f);
            u64 m = __ballot(iou > 0.45f);
            if (lane == word) myword = m;
        }
        if (lane == wi) diagArr[(b << 10) + i] = myword;                    // diagonal word
        else if (lane > wi && lane < 16) trib[Bw + r * s + (lane - wi - 1)] = myword;
    }
}

// ---------------- K4: per-batch sweep; triangle staged in LDS, parallel fold ----------------
__global__ __launch_bounds__(256) void sweep_kernel(const float4* __restrict__ soaA,
                                                    const float4* __restrict__ soaB,
                                                    const u64* __restrict__ tri,
                                                    const u64* __restrict__ diagArr,
                                                    float* __restrict__ out)
{
#pragma clang fp contract(off)
    __shared__ u64 tri_lds[TRI_WORDS];               // 61.44 KB
    __shared__ int sel[MAXDET];
    __shared__ int s_nsel;
    const int tid = threadIdx.x;
    const int b = blockIdx.x;

    // stage triangle (coalesced, 30 iters x 256 lanes)
    const u64* gtri = tri + (size_t)b * TRI_WORDS;
    for (int i = tid; i < TRI_WORDS; i += 256) tri_lds[i] = gtri[i];
    __syncthreads();

    if (tid < 64) {
        const int lane = tid;
        const u64* db = diagArr + (b << 10);

        // count of positive scores (sorted desc -> contiguous prefix)
        int nv = TK;
        for (int k = 0; k < 16; ++k) {
            float s = soaB[b * TK + (k << 6) + lane].y;
            u64 m = __ballot(s > 0.0f);
            if (m != ~0ull) { nv = (k << 6) + (int)__builtin_ctzll(~m); break; }
        }

        u64 removed = 0;                             // lane l owns word (l & 15), 4-replicated
        int nsel = 0;
        const int g = lane >> 4;                     // fold row-group 0..3
        const int word = lane & 15;
        u64 diag = db[lane];                         // window 0 diagonal words
        for (int w = 0; w < 16; ++w) {
            u64 dnext = (w < 15) ? db[((w + 1) << 6) + lane] : 0ull;
            u64 wv = __shfl(removed, w, 64);         // word w of removed
            int rem = nv - (w << 6);
            u64 validm = (rem >= 64) ? ~0ull : ((rem <= 0) ? 0ull : ((1ull << rem) - 1ull));
            u64 alive = validm & ~wv;
            u64 selbits = 0;
            while (alive != 0ull && nsel < MAXDET) {
                int i = (int)__builtin_ctzll(alive); // uniform: next greedy pick
                if (lane == 0) sel[nsel] = (w << 6) + i;
                ++nsel;
                selbits |= (1ull << i);
                u64 d = __shfl(diag, i, 64);         // row i's diagonal word (incl. self)
                alive &= ~d;
                alive &= ~(1ull << i);
            }
            // parallel fold from LDS: group g handles selected bits g, g+4, g+8, ...
            if (selbits != 0ull && w < 15) {
                const int Bw = triBase(w);
                const int s = 15 - w;
                u64 sb = selbits;
                if (g >= 1 && sb) sb &= sb - 1;      // drop exactly g leading bits
                if (g >= 2 && sb) sb &= sb - 1;
                if (g >= 3 && sb) sb &= sb - 1;
                u64 acc = 0;
                while (sb) {
                    int i = (int)__builtin_ctzll(sb);
                    if (word > w) acc |= tri_lds[Bw + i * s + (word - w - 1)];
                    sb &= sb - 1; if (sb) { sb &= sb - 1; if (sb) { sb &= sb - 1; if (sb) sb &= sb - 1; } }
                }
                acc |= __shfl_xor(acc, 16, 64);
                acc |= __shfl_xor(acc, 32, 64);
                removed |= acc;
            }
            diag = dnext;
            if (nsel >= MAXDET || rem <= 64) break;
        }
        if (lane == 0) s_nsel = nsel;
    }
    __syncthreads();

    // epilogue: scale_coords (gain=0.5, pad=(0,140)) + write 300 rows
    const int nsel = s_nsel;
    for (int r = tid; r < MAXDET; r += 256) {
        float* o = out + ((size_t)b * MAXDET + r) * 6;
        if (r < nsel) {
            int p = sel[r];
            float4 A = soaA[b * TK + p];
            float4 Bv = soaB[b * TK + p];
            float X1 = (A.x - 0.0f) / 0.5f;
            float Y1 = (A.y - 140.0f) / 0.5f;
            float X2 = (A.z - 0.0f) / 0.5f;
            float Y2 = (A.w - 140.0f) / 0.5f;
            X1 = fminf(fmaxf(X1, 0.0f), 1280.0f);
            Y1 = fminf(fmaxf(Y1, 0.0f), 720.0f);
            X2 = fminf(fmaxf(X2, 0.0f), 1280.0f);
            Y2 = fminf(fmaxf(Y2, 0.0f), 720.0f);
            o[0] = X1; o[1] = Y1; o[2] = X2; o[3] = Y2;
            o[4] = Bv.y; o[5] = Bv.z;
        } else {
            o[0] = 0.0f; o[1] = 0.0f; o[2] = 0.0f;
            o[3] = 0.0f; o[4] = 0.0f; o[5] = 0.0f;
        }
    }
}

extern "C" void kernel_launch(void* const* d_in, const int* in_sizes, int n_in,
                              void* d_out, int out_size, void* d_ws, size_t ws_size,
                              hipStream_t stream)
{
    const float* pred = (const float*)d_in[0];
    float* out = (float*)d_out;

    // workspace layout (high-water ~3.9 MB):
    //   [0, 3,225,600)          keys (u64 x 403200) -- dead after K2
    //   [0, 983,040)            tri  (u64 x 16 x 7680)  -- aliases keys, written after K2
    //   [983,040, 1,114,112)    diagArr (u64 x 16 x 1024)
    //   [3,225,600, +262,144)   soaA
    //   [3,487,744, +262,144)   soaB
    //   [3,749,888, +131,072)   ghist (u32 x 16 x 2048)
    u64* keys = (u64*)d_ws;
    u64* tri = (u64*)d_ws;
    u64* diagArr = (u64*)((char*)d_ws + 983040);
    float4* soaA = (float4*)((char*)d_ws + 3225600);
    float4* soaB = (float4*)((char*)d_ws + 3225600 + 262144);
    u32* ghist = (u32*)((char*)d_ws + 3749888);

    zero_kernel<<<32, 256, 0, stream>>>((uint4*)ghist);
    score_kernel<<<(NB * N_CAND) / 64, 256, 0, stream>>>(pred, keys, ghist);
    topk_kernel<<<NB, 1024, 0, stream>>>(pred, keys, ghist, soaA, soaB);
    mask_kernel<<<dim3(16, NB), 512, 0, stream>>>(soaA, soaB, tri, diagArr);
    sweep_kernel<<<NB, 256, 0, stream>>>(soaA, soaB, tri, diagArr, out);
}

// Round 9
// 119.720 us; speedup vs baseline: 1.2754x; 1.2754x over previous
//
#include <hip/hip_runtime.h>
#include <stdint.h>

#define N_CAND 25200
#define NB 16
#define ROW 85
#define TK 1024
#define MAXDET 300
#define CAP 2048
#define BITS_LO 0x3E800000u

typedef unsigned long long u64;
typedef unsigned int u32;

static __device__ __forceinline__ u64 u64min(u64 a, u64 b) { return a < b ? a : b; }
static __device__ __forceinline__ u64 u64max(u64 a, u64 b) { return a > b ? a : b; }

// ---------------- K1: score + key; global->LDS direct staging (no VGPR round-trip) ----------------
__global__ __launch_bounds__(256, 8) void score_kernel(const float* __restrict__ pred,
                                                       u64* __restrict__ keys)
{
#pragma clang fp contract(off)
    __shared__ float tile[64 * ROW];                 // 21.76 KB -> 7 blocks/CU (LDS cap)
    const int tid = threadIdx.x;
    const int row0 = blockIdx.x * 64;                // 6300 blocks
    const float4* src = (const float4*)(pred + (size_t)row0 * ROW);
    float4* dst = (float4*)tile;
    // async global->LDS, 16B/lane: lanes are contiguous so LDS dest = uniform base + lane*16
#pragma unroll
    for (int i = 0; i < 6; ++i) {
        int idx = tid + (i << 8);
        if (idx < (64 * ROW) / 4) {
            __builtin_amdgcn_global_load_lds(
                (const __attribute__((address_space(1))) void*)(src + idx),
                (__attribute__((address_space(3))) void*)(dst + idx),
                16, 0, 0);
        }
    }
    __syncthreads();                                 // compiler emits vmcnt(0) before barrier

    const int r = tid >> 2, sub = tid & 3;
    const float* rowp = tile + r * ROW;
    const float obj = rowp[4];                       // 4-lane broadcast
    const int base = 5 + sub * 20;
    float bv = obj * rowp[base];                     // products, exactly like reference
    int bi = base - 5;
#pragma unroll
    for (int c = 1; c < 20; ++c) {
        float p = obj * rowp[base + c];
        if (p > bv) { bv = p; bi = base - 5 + c; }   // strict > : first occurrence
    }
#pragma unroll
    for (int off = 1; off <= 2; off <<= 1) {         // merge 4 sub-lanes; tie -> lower idx
        float ov = __shfl_xor(bv, off, 64);
        int   oi = __shfl_xor(bi, off, 64);
        if (ov > bv || (ov == bv && oi < bi)) { bv = ov; bi = oi; }
    }
    if (sub == 0) {
        int w = row0 + r;
        u32 n = (u32)w % N_CAND;
        u64 key = 0;
        if (obj > 0.25f && bv > 0.25f)
            key = ((u64)__float_as_uint(bv) << 32) | (((u64)(25199u - n)) << 7) | (u32)bi;
        keys[w] = key;                               // desc sort => conf desc, n asc (ties)
    }
}

// ---------------- K2: per-batch histogram + suffix-sum + gather + hybrid bitonic sort -> SoA ----------------
__global__ __launch_bounds__(1024) void topk_kernel(const float* __restrict__ pred,
                                                    const u64* __restrict__ keys,
                                                    float4* __restrict__ soaA,
                                                    float4* __restrict__ soaB)
{
#pragma clang fp contract(off)
    __shared__ u64 sbuf[CAP];                        // 16 KB
    __shared__ u32 histA[2048];                      // 8 KB
    __shared__ u32 histB[2048];                      // 8 KB
    __shared__ u32 s_t;
    __shared__ int s_cnt;

    const int tid = threadIdx.x;
    const int b = blockIdx.x;
    const u64* kb = keys + (size_t)b * N_CAND;
    const float* pb = pred + (size_t)b * N_CAND * ROW;

    for (int i = tid; i < 2048; i += 1024) histA[i] = 0;
    if (tid == 0) { s_cnt = 0; s_t = 0; }
    __syncthreads();

    // Phase A: histogram of conf bits (valid conf in (0.25,1) -> bins 0..2047)
    for (int n = tid; n < N_CAND; n += 1024) {
        u32 bits = (u32)(kb[n] >> 32);
        if (bits) {
            int bin = (int)((bits - BITS_LO) >> 13);
            bin = bin < 0 ? 0 : (bin > 2047 ? 2047 : bin);
            atomicAdd(&histA[bin], 1u);
        }
    }
    __syncthreads();

    // Phase A2: parallel suffix sum (Hillis-Steele, 11 passes)
    u32* srcp = histA; u32* dstp = histB;
    for (int step = 1; step < 2048; step <<= 1) {
        for (int i = tid; i < 2048; i += 1024)
            dstp[i] = srcp[i] + ((i + step < 2048) ? srcp[i + step] : 0u);
        __syncthreads();
        u32* t = srcp; srcp = dstp; dstp = t;
    }
    for (int i = tid; i < 2048; i += 1024) {
        u32 S = srcp[i];
        if (S >= TK && (i == 2047 || srcp[i + 1] < TK)) s_t = (u32)i;
    }
    __syncthreads();
    const u32 thr = BITS_LO + (s_t << 13);

    // Phase B: gather candidates >= threshold bin
    for (int n = tid; n < N_CAND; n += 1024) {
        u64 k = kb[n];
        if ((u32)(k >> 32) >= thr) {
            int pos = atomicAdd(&s_cnt, 1);
            if (pos < CAP) sbuf[pos] = k;
        }
    }
    __syncthreads();
    int cnt = s_cnt; if (cnt > CAP) cnt = CAP;
    for (int i = tid; i < CAP; i += 1024) if (i >= cnt) sbuf[i] = 0ull;
    __syncthreads();

    // Phase C: hybrid bitonic sort ascending, 2 elems/thread
    {
        const int E0 = tid << 1;
        u64 e0 = sbuf[E0], e1 = sbuf[E0 + 1];
        for (int k = 2; k <= CAP; k <<= 1) {
            for (int j = k >> 1; j > 0; j >>= 1) {
                const bool asc = ((E0 & k) == 0);
                if (j >= 128) {
                    __syncthreads();
                    sbuf[E0] = e0; sbuf[E0 + 1] = e1;
                    __syncthreads();
                    u64 p0 = sbuf[E0 ^ j], p1 = sbuf[(E0 + 1) ^ j];
                    const bool low = ((E0 & j) == 0);
                    e0 = (asc == low) ? u64min(e0, p0) : u64max(e0, p0);
                    e1 = (asc == low) ? u64min(e1, p1) : u64max(e1, p1);
                } else if (j >= 2) {
                    const int l = j >> 1;
                    u64 p0 = __shfl_xor(e0, l, 64);
                    u64 p1 = __shfl_xor(e1, l, 64);
                    const bool low = ((E0 & j) == 0);
                    e0 = (asc == low) ? u64min(e0, p0) : u64max(e0, p0);
                    e1 = (asc == low) ? u64min(e1, p1) : u64max(e1, p1);
                } else {
                    u64 mn = u64min(e0, e1), mx = u64max(e0, e1);
                    e0 = asc ? mn : mx;
                    e1 = asc ? mx : mn;
                }
            }
        }
        __syncthreads();
        sbuf[E0] = e0; sbuf[E0 + 1] = e1;
        __syncthreads();
    }

    // Phase D: extract top-1024 (slot 0 = best), gather boxes, write SoA
    {
        const int i = tid;
        u64 k = sbuf[CAP - 1 - i];
        u32 bits = (u32)(k >> 32);
        float4 A, Bv;
        if (bits) {
            u32 lo = (u32)k;
            u32 n = 25199u - (lo >> 7);
            float c = (float)(lo & 127u);
            const float* rp = pb + (size_t)n * ROW;
            float x = rp[0], y = rp[1], ww = rp[2], hh = rp[3];
            float hw = ww * 0.5f, hv = hh * 0.5f;
            float x1 = x - hw, y1 = y - hv, x2 = x + hw, y2 = y + hv;
            float offc = c * 4096.0f;
            float area = ((x2 + offc) - (x1 + offc)) * ((y2 + offc) - (y1 + offc));
            A = make_float4(x1, y1, x2, y2);
            Bv = make_float4(area, __uint_as_float(bits), c, 0.0f);
        } else {
            A = make_float4(0.0f, 0.0f, 0.0f, 0.0f);
            Bv = make_float4(0.0f, -1.0f, 0.0f, 0.0f);
        }
        soaA[b * TK + i] = A;
        soaB[b * TK + i] = Bv;
    }
}

// ---------------- K3: 1024x1024 suppression bitmask matrix (whole-GPU parallel) ----------------
__global__ __launch_bounds__(512) void mask_kernel(const float4* __restrict__ soaA,
                                                   const float4* __restrict__ soaB,
                                                   u64* __restrict__ masks)
{
#pragma clang fp contract(off)
    __shared__ float4 cA[TK];                        // 16 KB
    __shared__ float4 cB[TK];                        // 16 KB
    const int tid = threadIdx.x;
    const int b = blockIdx.y;
    const int rbase = blockIdx.x * 64;
    for (int i = tid; i < TK; i += 512) { cA[i] = soaA[b * TK + i]; cB[i] = soaB[b * TK + i]; }
    __syncthreads();

    const int wave = tid >> 6, lane = tid & 63;
    for (int rr = 0; rr < 8; ++rr) {
        int i = rbase + (wave << 3) + rr;
        float4 P = cA[i]; float4 Pb = cB[i];         // broadcast reads
        float offp = Pb.z * 4096.0f;
        float px1 = P.x + offp, py1 = P.y + offp, px2 = P.z + offp, py2 = P.w + offp;
        float parea = Pb.x;
        u64 myword = 0;
        for (int word = 0; word < 16; ++word) {
            int j = (word << 6) + lane;
            float4 Q = cA[j]; float4 Qb = cB[j];
            float offj = Qb.z * 4096.0f;
            float qx1 = Q.x + offj, qy1 = Q.y + offj, qx2 = Q.z + offj, qy2 = Q.w + offj;
            float ltx = fmaxf(px1, qx1), lty = fmaxf(py1, qy1);
            float rbx = fminf(px2, qx2), rby = fminf(py2, qy2);
            float w2 = fmaxf(rbx - ltx, 0.0f), h2 = fmaxf(rby - lty, 0.0f);
            float inter = w2 * h2;
            float iou = inter / (parea + Qb.x - inter + 1e-9f);
            u64 m = __ballot(iou > 0.45f);
            if (lane == word) myword = m;
        }
        if (lane < 16) masks[((size_t)(b * TK + i) << 4) + lane] = myword;  // coalesced 128B
    }
}

// ---------------- K4: per-batch single-wave greedy sweep + output ----------------
__global__ __launch_bounds__(64) void sweep_kernel(const float4* __restrict__ soaA,
                                                   const float4* __restrict__ soaB,
                                                   const u64* __restrict__ masks,
                                                   float* __restrict__ out)
{
#pragma clang fp contract(off)
    __shared__ int sel[MAXDET];
    const int lane = threadIdx.x;
    const int b = blockIdx.x;
    const u64* mb = masks + ((size_t)(b * TK) << 4);

    // count of positive scores (sorted desc -> contiguous prefix)
    int nv = TK;
    for (int k = 0; k < 16; ++k) {
        float s = soaB[b * TK + (k << 6) + lane].y;
        u64 m = __ballot(s > 0.0f);
        if (m != ~0ull) { nv = (k << 6) + (int)__builtin_ctzll(~m); break; }
    }

    u64 removed = 0;                                 // lane w (w<16) owns word w
    int nsel = 0;
    bool done = (nv == 0);
    const int li = lane & 15;

    u64 cur[8], nxt[8];
#pragma unroll
    for (int r = 0; r < 8; ++r) cur[r] = mb[((size_t)r << 4) + li];

    for (int c = 0; c < 128 && !done; ++c) {
        int nb0 = (c + 1) << 3;
#pragma unroll
        for (int r = 0; r < 8; ++r) {                // prefetch next chunk
            int i2 = nb0 + r; if (i2 > TK - 1) i2 = TK - 1;
            nxt[r] = mb[((size_t)i2 << 4) + li];
        }
#pragma unroll
        for (int r = 0; r < 8; ++r) {
            int i = (c << 3) + r;
            if (!done && i < nv) {
                u64 wv = __shfl(removed, i >> 6, 64);
                if (!((wv >> (i & 63)) & 1ull)) {    // alive -> select
                    if (lane == 0) sel[nsel] = i;
                    removed |= cur[r];
                    ++nsel;
                    if (nsel == MAXDET) done = true;
                }
            } else if (i >= nv) done = true;
        }
#pragma unroll
        for (int r = 0; r < 8; ++r) cur[r] = nxt[r];
    }
    __syncthreads();

    // epilogue: scale_coords (gain=0.5, pad=(0,140)) + write 300 rows
    for (int r = lane; r < MAXDET; r += 64) {
        float* o = out + ((size_t)b * MAXDET + r) * 6;
        if (r < nsel) {
            int p = sel[r];
            float4 A = soaA[b * TK + p];
            float4 Bv = soaB[b * TK + p];
            float X1 = (A.x - 0.0f) / 0.5f;
            float Y1 = (A.y - 140.0f) / 0.5f;
            float X2 = (A.z - 0.0f) / 0.5f;
            float Y2 = (A.w - 140.0f) / 0.5f;
            X1 = fminf(fmaxf(X1, 0.0f), 1280.0f);
            Y1 = fminf(fmaxf(Y1, 0.0f), 720.0f);
            X2 = fminf(fmaxf(X2, 0.0f), 1280.0f);
            Y2 = fminf(fmaxf(Y2, 0.0f), 720.0f);
            o[0] = X1; o[1] = Y1; o[2] = X2; o[3] = Y2;
            o[4] = Bv.y; o[5] = Bv.z;
        } else {
            o[0] = 0.0f; o[1] = 0.0f; o[2] = 0.0f;
            o[3] = 0.0f; o[4] = 0.0f; o[5] = 0.0f;
        }
    }
}

extern "C" void kernel_launch(void* const* d_in, const int* in_sizes, int n_in,
                              void* d_out, int out_size, void* d_ws, size_t ws_size,
                              hipStream_t stream)
{
    const float* pred = (const float*)d_in[0];
    float* out = (float*)d_out;

    // workspace layout (high-water 3.75 MB):
    //   [0, 3,225,600)          keys (u64 x 403200)  -- dead after K2
    //   [0, 2,097,152)          masks (u64 x 262144) -- aliases keys, written by K3 after K2
    //   [3,225,600, +262,144)   soaA (float4 x 16384)
    //   [3,487,744, +262,144)   soaB (float4 x 16384)
    u64* keys = (u64*)d_ws;
    u64* masks = (u64*)d_ws;
    float4* soaA = (float4*)((char*)d_ws + 3225600);
    float4* soaB = (float4*)((char*)d_ws + 3225600 + 262144);

    score_kernel<<<(NB * N_CAND) / 64, 256, 0, stream>>>(pred, keys);
    topk_kernel<<<NB, 1024, 0, stream>>>(pred, keys, soaA, soaB);
    mask_kernel<<<dim3(16, NB), 512, 0, stream>>>(soaA, soaB, masks);
    sweep_kernel<<<NB, 64, 0, stream>>>(soaA, soaB, masks, out);
}